// Round 7
// baseline (283.644 us; speedup 1.0000x reference)
//
#include <hip/hip_runtime.h>

#define TOKENS 8192
#define D_IN   4096
#define D_OUT  4096

typedef _Float16 f16;
typedef __attribute__((ext_vector_type(8))) _Float16 half8;
typedef __attribute__((ext_vector_type(4))) float    f32x4;
typedef __attribute__((address_space(3))) char       lds_char;

// ---------------- conversion kernels ----------------

__global__ void cvt_x_kernel(const float* __restrict__ x, f16* __restrict__ xh) {
    size_t i = ((size_t)blockIdx.x * blockDim.x + threadIdx.x) * 4;
    float4 v = *reinterpret_cast<const float4*>(x + i);
    union { f16 h[4]; uint2 u; } p;
    p.h[0] = (f16)v.x; p.h[1] = (f16)v.y; p.h[2] = (f16)v.z; p.h[3] = (f16)v.w;
    *reinterpret_cast<uint2*>(xh + i) = p.u;
}

__global__ void cvt_w_kernel(const int* __restrict__ w, f16* __restrict__ wh,
                             const float* __restrict__ scale_p,
                             const int* __restrict__ zp_p) {
    size_t i = ((size_t)blockIdx.x * blockDim.x + threadIdx.x) * 4;
    float s = scale_p[0];
    float z = (float)zp_p[0];
    int4 v = *reinterpret_cast<const int4*>(w + i);
    union { f16 h[4]; uint2 u; } p;
    p.h[0] = (f16)(((float)v.x - z) * s);
    p.h[1] = (f16)(((float)v.y - z) * s);
    p.h[2] = (f16)(((float)v.z - z) * s);
    p.h[3] = (f16)(((float)v.w - z) * s);
    *reinterpret_cast<uint2*>(wh + i) = p.u;
}

// ---------------- GEMM: 256x256 tile, BK=64, 8 waves, 1-cluster-ahead pipe -
// C[t][o] = sum_k A[t][k]*B[o][k];  A=[M][K] f16, B=[N][K] f16 (both K-major).
// LDS: 2 dbuf x (A 32KB + B 32KB) = 128 KB, [256][64] f16 rows with XOR
// swizzle phys_colbyte = logical ^ ((row&7)<<4); global_load_lds writes
// linearly, swizzle pre-applied to the per-lane GLOBAL source column.
//
// R7: every ds_read is issued ONE MFMA-CLUSTER BEFORE its consumer so the
// LDS service hides in the previous cluster's shadow (R6 post-mortem: reads
// and MFMA summed, 47% MfmaUtil). Entering tile t, regs already hold a0,b0.
//   top:  read b1 (hides under MFMA 00/01); stage B-quads of t+1 (4 DMAs)
//   P1:   VMCNT(4)+BAR  (drain A13(t))  -> read a1 (hides under MFMA 11);
//         stage A02(t+1); FENCE; stage A13(t+1)
//   P2:   VMCNT(2)+BAR  (drain B*4+A02 of t+1, leave A13') -> prefetch
//         a0,b0n of t+1 from the just-drained buffer (hides under MFMA 10)
// Protocol (R5 lesson): drain own vmcnt -> s_barrier -> ds_read, at BOTH
// consume points. All reads of buf(t&1) complete before P2(t) (a1 forced by
// MFMA(1,1)'s lgkm wait); staging of buf(t&1) starts after P2(t). Ledger:
// [A13]=2 +4B =6 ; VMCNT(4) drains A13 ; +A02=6 ; FENCE ; +A13'=8 ;
// VMCNT(2) drains B*4+A02, leaves A13'=2 = next-tile entry state.
// Peel (t=NT-1): enters with 2 outstanding, stages nothing -> VMCNT(0)+BAR
// before a1 reads (R2 lesson: counted drain no-ops when queue is short).

#define BM 256
#define BN 256
#define BK 64
#define NT (D_IN / BK)      // 64 K-tiles
#define LDS_BUF   65536
#define LDS_B_OFF 32768

__device__ __forceinline__ void stage16(const f16* g, lds_char* l) {
    __builtin_amdgcn_global_load_lds(
        (const __attribute__((address_space(1))) void*)g,
        (__attribute__((address_space(3))) void*)l, 16, 0, 0);
}

#define LDS_LOAD8(p) (*(const __attribute__((address_space(3))) half8*)(p))

#define LOAD_AQ(DST, BUF, QM)                                               \
    do { _Pragma("unroll")                                                  \
        for (int fm = 0; fm < 4; ++fm) {                                    \
            int rr = wr * 128 + (QM) * 64 + fm * 16 + lr;                   \
            _Pragma("unroll")                                               \
            for (int ks = 0; ks < 2; ++ks)                                  \
                DST[fm][ks] = LDS_LOAD8((BUF) + rr * 128 +                  \
                                        ((cb0 + ks * 64) ^ swzr));          \
        } } while (0)

#define LOAD_BQ(DST, BUF, QN)                                               \
    do { _Pragma("unroll")                                                  \
        for (int fn = 0; fn < 2; ++fn) {                                    \
            int rr = wc * 64 + (QN) * 32 + fn * 16 + lr;                    \
            _Pragma("unroll")                                               \
            for (int ks = 0; ks < 2; ++ks)                                  \
                DST[fn][ks] = LDS_LOAD8((BUF) + rr * 128 +                  \
                                        ((cb0 + ks * 64) ^ swzr));          \
        } } while (0)

#define MFMA_Q(QM, QN, AV, BV)                                              \
    do { _Pragma("unroll")                                                  \
        for (int fm = 0; fm < 4; ++fm) {                                    \
            _Pragma("unroll")                                               \
            for (int fn = 0; fn < 2; ++fn) {                                \
                _Pragma("unroll")                                           \
                for (int ks = 0; ks < 2; ++ks)                              \
                    acc[(QM)*4+fm][(QN)*2+fn] =                             \
                        __builtin_amdgcn_mfma_f32_16x16x32_f16(             \
                            AV[fm][ks], BV[fn][ks],                         \
                            acc[(QM)*4+fm][(QN)*2+fn], 0, 0, 0);            \
            }                                                               \
        } } while (0)

#define FENCE()    asm volatile("" ::: "memory")
#define BAR()      __builtin_amdgcn_s_barrier()
#define VMCNT(N)   asm volatile("s_waitcnt vmcnt(" #N ")" ::: "memory")

__global__ __launch_bounds__(512, 2)
void gemm_pipe(const f16* __restrict__ A, const f16* __restrict__ B,
               const float* __restrict__ bias,
               const float* __restrict__ oscale_p, const int* __restrict__ ozp_p,
               float* __restrict__ C)
{
    __shared__ __align__(1024) char smem_[2 * LDS_BUF];   // 128 KiB
    lds_char* smem = (lds_char*)smem_;
    constexpr int K = D_IN, N = D_OUT;

    // XCD-aware bijective swizzle (grid = 512, divisible by 8)
    int nwg = gridDim.x;
    int cpx = nwg >> 3;
    int bid = blockIdx.x;
    int swz = (bid & 7) * cpx + (bid >> 3);
    int ntn = N / BN;                        // 16
    int m0 = (swz / ntn) * BM;
    int n0 = (swz % ntn) * BN;

    int tid = threadIdx.x;
    int l   = tid & 63;
    int wv  = tid >> 6;                      // 0..7
    int wr  = wv >> 2;                       // 0..1 (M)
    int wc  = wv & 3;                        // 0..3 (N)

    // staging: lane l -> row_in_block = l>>3, phys slot = l&7;
    // pre-swizzled global col = ((l&7) ^ (l>>3)) * 8 f16.
    int srow = wv * 8 + (l >> 3);
    int scol = ((l & 7) ^ (l >> 3)) * 8;
    const f16* gA = A + (size_t)(m0 + srow) * K + scol;
    const f16* gB = B + (size_t)(n0 + srow) * K + scol;
    lds_char* dstbase = smem + wv * 1024 + l * 16;

    // read-side per-lane constants
    int lr   = l & 15;
    int swzr = (l & 7) << 4;
    int cb0  = (l >> 4) * 16;

    f32x4 acc[8][4] = {};                    // [qm*4+fm][qn*2+fn]
    half8 a0[4][2], a1[4][2], b0[2][2], b0n[2][2], b1[2][2];

    // ---- prologue: stage tile 0 -> buffer 0, drain, barrier, preload a0/b0
    #pragma unroll
    for (int q = 0; q < 4; ++q) stage16(gA + (size_t)q * 64 * K, dstbase + q * 8192);
    #pragma unroll
    for (int q = 0; q < 4; ++q) stage16(gB + (size_t)q * 64 * K, dstbase + LDS_B_OFF + q * 8192);
    VMCNT(0);
    BAR();
    {
        const lds_char* bufA = smem;
        const lds_char* bufB = smem + LDS_B_OFF;
        LOAD_AQ(a0, bufA, 0);
        LOAD_BQ(b0, bufB, 0);
    }

    for (int t = 0; t < NT - 1; ++t) {
        const lds_char* bufA  = smem + (t & 1) * LDS_BUF;
        const lds_char* bufB  = bufA + LDS_B_OFF;
        const lds_char* bufAn = smem + ((t + 1) & 1) * LDS_BUF;
        const lds_char* bufBn = bufAn + LDS_B_OFF;
        lds_char* dst = dstbase + ((t + 1) & 1) * LDS_BUF;
        const f16* nA = gA + (size_t)(t + 1) * BK;
        const f16* nB = gB + (size_t)(t + 1) * BK;

        // ---- top: b1 reads hide under MFMA 00/01; stage all B of t+1
        LOAD_BQ(b1, bufB, 1);
        stage16(nB,                      dst + LDS_B_OFF);
        stage16(nB + (size_t)64 * K,     dst + LDS_B_OFF + 8192);
        stage16(nB + (size_t)128 * K,    dst + LDS_B_OFF + 2 * 8192);
        stage16(nB + (size_t)192 * K,    dst + LDS_B_OFF + 3 * 8192);
        MFMA_Q(0, 0, a0, b0);
        MFMA_Q(0, 1, a0, b1);

        // ---- P1: A13(t) consume point (drain -> barrier -> read)
        VMCNT(4);
        BAR();
        LOAD_AQ(a1, bufA, 1);            // hides under MFMA 11
        stage16(nA,                      dst);
        stage16(nA + (size_t)128 * K,    dst + 2 * 8192);
        FENCE();                         // keep A13' issued after A02 (ledger)
        stage16(nA + (size_t)64 * K,     dst + 8192);
        stage16(nA + (size_t)192 * K,    dst + 3 * 8192);
        MFMA_Q(1, 1, a1, b1);

        // ---- P2: next-tile buffer ready (drain -> barrier -> read)
        VMCNT(2);
        BAR();
        LOAD_AQ(a0, bufAn, 0);           // next tile's first-cluster operands,
        LOAD_BQ(b0n, bufBn, 0);          // hide under MFMA 10
        MFMA_Q(1, 0, a1, b0);

        #pragma unroll
        for (int fn = 0; fn < 2; ++fn)
            #pragma unroll
            for (int ks = 0; ks < 2; ++ks)
                b0[fn][ks] = b0n[fn][ks];
    }

    // ===== peeled final tile (t = NT-1): no staging =====
    {
        const lds_char* bufA = smem + ((NT - 1) & 1) * LDS_BUF;
        const lds_char* bufB = bufA + LDS_B_OFF;

        LOAD_BQ(b1, bufB, 1);
        MFMA_Q(0, 0, a0, b0);
        MFMA_Q(0, 1, a0, b1);

        VMCNT(0);     // A13 of the final tile still in flight at entry
        BAR();        // collective: every wave's slices resident
        LOAD_AQ(a1, bufA, 1);
        MFMA_Q(1, 1, a1, b1);
        MFMA_Q(1, 0, a1, b0);
    }

    // ---- epilogue: bias + fake-quantize (round-half-even = jnp.round)
    float os  = oscale_p[0];
    float ozp = (float)ozp_p[0];
    float inv = 1.0f / os;
    #pragma unroll
    for (int qm = 0; qm < 2; ++qm) {
        #pragma unroll
        for (int fm = 0; fm < 4; ++fm) {
            int rowb = m0 + wr * 128 + qm * 64 + fm * 16 + (l >> 4) * 4;
            #pragma unroll
            for (int qn = 0; qn < 2; ++qn) {
                #pragma unroll
                for (int fn = 0; fn < 2; ++fn) {
                    int col = n0 + wc * 64 + qn * 32 + fn * 16 + lr;
                    float bv = bias[col];
                    f32x4 v = acc[qm * 4 + fm][qn * 2 + fn];
                    #pragma unroll
                    for (int j = 0; j < 4; ++j) {
                        float o = v[j] + bv;
                        float q = rintf(o * inv) + ozp;
                        q = fminf(fmaxf(q, 0.0f), 255.0f);
                        C[(size_t)(rowb + j) * N + col] = (q - ozp) * os;
                    }
                }
            }
        }
    }
}

// ---------------- launch ----------------

extern "C" void kernel_launch(void* const* d_in, const int* in_sizes, int n_in,
                              void* d_out, int out_size, void* d_ws, size_t ws_size,
                              hipStream_t stream) {
    const float* x      = (const float*)d_in[0];
    const int*   w8     = (const int*)d_in[1];
    const float* wscale = (const float*)d_in[2];
    const int*   wzp    = (const int*)d_in[3];
    const float* bias   = (const float*)d_in[4];
    const float* oscale = (const float*)d_in[5];
    const int*   ozp    = (const int*)d_in[6];
    float* out = (float*)d_out;

    const size_t x_elems = (size_t)TOKENS * D_IN;
    const size_t w_elems = (size_t)D_OUT * D_IN;
    const size_t need = (x_elems + w_elems) * sizeof(f16);
    if (ws_size < need) return;

    f16* xh = (f16*)d_ws;
    f16* wh = xh + x_elems;

    {
        int blocks = (int)(x_elems / 4 / 256);
        cvt_x_kernel<<<blocks, 256, 0, stream>>>(x, xh);
    }
    {
        int blocks = (int)(w_elems / 4 / 256);
        cvt_w_kernel<<<blocks, 256, 0, stream>>>(w8, wh, wscale, wzp);
    }
    {
        int grid = (TOKENS / BM) * (D_OUT / BN);   // 32 * 16 = 512, %8 == 0
        gemm_pipe<<<grid, 512, 0, stream>>>(xh, wh, bias, oscale, ozp, out);
    }
}